// Round 5
// baseline (72.813 us; speedup 1.0000x reference)
//
#include <hip/hip_runtime.h>

typedef unsigned short u16;
typedef unsigned int   u32;
typedef short s8v  __attribute__((ext_vector_type(8)));   // 8 bf16 (4 VGPR)
typedef float f16v __attribute__((ext_vector_type(16)));  // 32x32 acc
typedef unsigned int u32x4 __attribute__((ext_vector_type(4)));

#define ROWBYTES 4224                 // 4 c-chunks * (66 px * 16 B)
#define NROWS    10                   // 8 output rows + 2 halo
#define LDS_BYTES (NROWS * ROWBYTES)  // 42240 -> 3 blocks/CU

__device__ inline u16 f2bf(float f) {
    u32 u = __builtin_bit_cast(u32, f);
    u += 0x7FFFu + ((u >> 16) & 1u);   // RNE; inputs finite
    return (u16)(u >> 16);
}
__device__ inline u32 pk2(float lo, float hi) {
    return (u32)f2bf(lo) | ((u32)f2bf(hi) << 16);
}

// Fused conv: stage 10-row NHWC-bf16 tile to LDS (chunked [c/8][px][16B] layout;
// staging writes are contiguous b128 -> conflict-free), ONE barrier, 8 MFMA rows.
// Block: 256 thr = 4 waves; owns 32o x 64w x 8h. Grid: 16n*32hs*4wb = 2048.
__global__ __launch_bounds__(256, 3) void k_fused(const float* __restrict__ x,
                                                  const float* __restrict__ wgt,
                                                  const float* __restrict__ bias,
                                                  const float* __restrict__ scale_p,
                                                  float* __restrict__ out) {
    __shared__ __align__(16) char lds[LDS_BYTES];

    const int b    = blockIdx.x;
    const int wb   = b & 3;
    const int hs   = (b >> 2) & 31;
    const int n    = b >> 7;
    const int w0   = wb << 6;
    const int h0   = hs << 3;
    const int t    = threadIdx.x;
    const int l    = t & 63;
    const int wave = t >> 6;
    const int g    = l >> 5;
    const int ln   = l & 31;

    // ---- weight repack into LDS overlay: [o][c][9] f32 -> [tap][o*32+c] bf16
    {
        u16* wl = (u16*)lds;
        #pragma unroll
        for (int k = 0; k < 36; ++k) {
            const int idx = t + (k << 8);
            const int tap = idx % 9;
            const int oc  = idx / 9;
            wl[tap * 1024 + oc] = f2bf(wgt[idx]);
        }
    }
    __syncthreads();

    // A frags: wt[tap][o=ln][c = q*16 + g*8 + e]
    s8v A[9][2];
    {
        const u16* wl = (const u16*)lds;
        #pragma unroll
        for (int tap = 0; tap < 9; ++tap)
            #pragma unroll
            for (int q = 0; q < 2; ++q)
                A[tap][q] = *(const s8v*)(wl + tap * 1024 + ln * 32 + q * 16 + g * 8);
    }
    const float scale = scale_p[0];
    float bias_r[16];
    #pragma unroll
    for (int rg = 0; rg < 16; ++rg) bias_r[rg] = bias[(rg & 3) + 8 * (rg >> 2) + 4 * g];
    __syncthreads();   // weight overlay free

    const float* xbase = x + ((size_t)n << 21);           // n*32*65536

    // ---- halo px (ps=0, ps=65) first: scattered, long-latency -> overlap main
    if (t < 80) {
        const int r    = t % 10;
        const int side = (t / 10) & 1;
        const int cc   = t / 20;
        const int hin  = h0 - 1 + r;
        const int wg   = w0 - 1 + side * 65;
        u32 q0 = 0, q1 = 0, q2 = 0, q3 = 0;
        if (hin >= 0 && hin < 256 && wg >= 0 && wg < 256) {
            const float* p = xbase + (size_t)(cc * 8) * 65536 + (size_t)hin * 256 + wg;
            q0 = pk2(p[0],      p[65536]);
            q1 = pk2(p[131072], p[196608]);
            q2 = pk2(p[262144], p[327680]);
            q3 = pk2(p[393216], p[458752]);
        }
        *(u32x4*)(lds + r * ROWBYTES + cc * 1056 + side * 1040) = u32x4{q0, q1, q2, q3};
    }

    // ---- main staging: wave = c-chunk; lane l -> px w0+l (ps=l+1).
    // 8 coalesced b32 loads (8 channels of one px) -> 1 contiguous b128 write.
    {
        const float* pb = xbase + (size_t)(wave * 8) * 65536 + w0 + l;
        char* ldst = lds + wave * 1056 + ((l + 1) << 4);
        #pragma unroll
        for (int r = 0; r < NROWS; ++r) {
            const int hin = h0 - 1 + r;
            u32 q0 = 0, q1 = 0, q2 = 0, q3 = 0;
            if (hin >= 0 && hin < 256) {
                const float* p = pb + (size_t)hin * 256;
                const float c0 = p[0],      c1 = p[65536],  c2 = p[131072], c3 = p[196608];
                const float c4 = p[262144], c5 = p[327680], c6 = p[393216], c7 = p[458752];
                q0 = pk2(c0, c1); q1 = pk2(c2, c3); q2 = pk2(c4, c5); q3 = pk2(c6, c7);
            }
            *(u32x4*)(ldst + r * ROWBYTES) = u32x4{q0, q1, q2, q3};
        }
    }
    __syncthreads();   // the only full barrier before compute

    // ---- compute: each wave does 2 output rows, barrier-free
    #pragma unroll
    for (int i = 0; i < 2; ++i) {
        const int hr = (wave << 1) + i;                   // 0..7

        f16v acc0, acc1;
        #pragma unroll
        for (int rg = 0; rg < 16; ++rg) { acc0[rg] = 0.f; acc1[rg] = 0.f; }

        #pragma unroll
        for (int kh = 0; kh < 3; ++kh) {
            const char* rowp = lds + (hr + kh) * ROWBYTES + g * 1056 + (ln << 4);
            #pragma unroll
            for (int kw = 0; kw < 3; ++kw) {
                const int tap = kh * 3 + kw;
                #pragma unroll
                for (int q = 0; q < 2; ++q) {
                    const char* pB = rowp + q * 2112 + (kw << 4);
                    const s8v b0 = *(const s8v*)pB;           // px = w0+ln+kw-1
                    const s8v b1 = *(const s8v*)(pB + 512);   // px +32
                    acc0 = __builtin_amdgcn_mfma_f32_32x32x16_bf16(A[tap][q], b0, acc0, 0, 0, 0);
                    acc1 = __builtin_amdgcn_mfma_f32_32x32x16_bf16(A[tap][q], b1, acc1, 0, 0, 0);
                }
            }
        }

        // epilogue: D col(px)=ln, row(o)=(rg&3)+8*(rg>>2)+4*g ; nt streaming stores
        const int h = h0 + hr;
        float* op = out + ((size_t)n << 21) + (size_t)h * 256 + w0 + ln;
        #pragma unroll
        for (int rg = 0; rg < 16; ++rg) {
            const int o = (rg & 3) + 8 * (rg >> 2) + 4 * g;
            __builtin_nontemporal_store(scale * acc0[rg] + bias_r[rg], op + (size_t)o * 65536);
            __builtin_nontemporal_store(scale * acc1[rg] + bias_r[rg], op + (size_t)o * 65536 + 32);
        }
    }
}

extern "C" void kernel_launch(void* const* d_in, const int* in_sizes, int n_in,
                              void* d_out, int out_size, void* d_ws, size_t ws_size,
                              hipStream_t stream) {
    const float* x     = (const float*)d_in[0];
    const float* wgt   = (const float*)d_in[1];
    const float* bias  = (const float*)d_in[2];
    const float* scale = (const float*)d_in[3];
    float* out = (float*)d_out;
    k_fused<<<dim3(2048), dim3(256), 0, stream>>>(x, wgt, bias, scale, out);
}

// Round 6
// 58.077 us; speedup vs baseline: 1.2537x; 1.2537x over previous
//
#include <hip/hip_runtime.h>

typedef unsigned short u16;
typedef unsigned int   u32;
typedef short s8v  __attribute__((ext_vector_type(8)));   // 8 bf16 (4 VGPR)
typedef float f16v __attribute__((ext_vector_type(16)));  // 32x32 acc
typedef unsigned int u32x4 __attribute__((ext_vector_type(4)));

#define ROWBYTES 4224                 // 4 c-chunks * (66 px * 16 B)
#define NROWS    18                   // 16 output rows + 2 halo
#define LDS_BYTES (NROWS * ROWBYTES)  // 76032 -> 2 blocks/CU

__device__ inline u16 f2bf(float f) {
    u32 u = __builtin_bit_cast(u32, f);
    u += 0x7FFFu + ((u >> 16) & 1u);   // RNE; inputs finite
    return (u16)(u >> 16);
}
__device__ inline u32 pk2(float lo, float hi) {
    return (u32)f2bf(lo) | ((u32)f2bf(hi) << 16);
}

// Fused conv: stage 18-row NHWC-bf16 tile in LDS (contiguous b128 staging
// writes), ONE barrier, 16 MFMA rows. XCD-swizzled blockIdx so the 4 wb-
// sibling blocks of one (n,hs) band share an XCD L2 -> 1KB HBM bursts.
// Block: 256 thr = 4 waves; owns 32o x 64w x 16h. Grid: 16n*16hs*4wb = 1024.
__global__ __launch_bounds__(256, 2) void k_fused(const float* __restrict__ x,
                                                  const float* __restrict__ wgt,
                                                  const float* __restrict__ bias,
                                                  const float* __restrict__ scale_p,
                                                  float* __restrict__ out) {
    __shared__ __align__(16) char lds[LDS_BYTES];

    // bijective XCD swizzle: 8 consecutive logical blocks -> same XCD
    const int b    = ((blockIdx.x & 7) << 7) | (blockIdx.x >> 3);   // grid 1024
    const int wb   = b & 3;
    const int hs   = (b >> 2) & 15;
    const int n    = b >> 6;
    const int w0   = wb << 6;
    const int h0   = hs << 4;
    const int t    = threadIdx.x;
    const int l    = t & 63;
    const int wave = t >> 6;
    const int g    = l >> 5;
    const int ln   = l & 31;

    // ---- weight repack into LDS overlay: [o][c][9] f32 -> [tap][o*32+c] bf16
    {
        u16* wl = (u16*)lds;
        #pragma unroll
        for (int k = 0; k < 36; ++k) {
            const int idx = t + (k << 8);
            const int tap = idx % 9;
            const int oc  = idx / 9;
            wl[tap * 1024 + oc] = f2bf(wgt[idx]);
        }
    }
    __syncthreads();

    // A frags: wt[tap][o=ln][c = q*16 + g*8 + e]
    s8v A[9][2];
    {
        const u16* wl = (const u16*)lds;
        #pragma unroll
        for (int tap = 0; tap < 9; ++tap)
            #pragma unroll
            for (int q = 0; q < 2; ++q)
                A[tap][q] = *(const s8v*)(wl + tap * 1024 + ln * 32 + q * 16 + g * 8);
    }
    const float scale = scale_p[0];
    float bias_r[16];
    #pragma unroll
    for (int rg = 0; rg < 16; ++rg) bias_r[rg] = bias[(rg & 3) + 8 * (rg >> 2) + 4 * g];
    __syncthreads();   // weight overlay free

    const float* xbase = x + ((size_t)n << 21);           // n*32*65536

    // ---- halo px (ps=0, ps=65): 144 gather threads, u32x4 writes
    if (t < 144) {
        const int cc   = t / 36;
        const int rem  = t - cc * 36;
        const int side = rem / 18;
        const int r    = rem - side * 18;
        const int hin  = h0 - 1 + r;
        const int wg   = w0 - 1 + side * 65;
        u32 q0 = 0, q1 = 0, q2 = 0, q3 = 0;
        if (hin >= 0 && hin < 256 && wg >= 0 && wg < 256) {
            const float* p = xbase + (size_t)(cc * 8) * 65536 + (size_t)hin * 256 + wg;
            q0 = pk2(p[0],      p[65536]);
            q1 = pk2(p[131072], p[196608]);
            q2 = pk2(p[262144], p[327680]);
            q3 = pk2(p[393216], p[458752]);
        }
        *(u32x4*)(lds + r * ROWBYTES + cc * 1056 + side * 1040) = u32x4{q0, q1, q2, q3};
    }

    // ---- main staging: wave = c-chunk; lane l -> px w0+l (ps=l+1).
    // 8 coalesced b32 loads (8 channels of one px) -> 1 contiguous b128 write.
    {
        const float* pb = xbase + (size_t)(wave * 8) * 65536 + w0 + l;
        char* ldst = lds + wave * 1056 + ((l + 1) << 4);
        #pragma unroll
        for (int r = 0; r < NROWS; ++r) {
            const int hin = h0 - 1 + r;
            u32 q0 = 0, q1 = 0, q2 = 0, q3 = 0;
            if (hin >= 0 && hin < 256) {
                const float* p = pb + (size_t)hin * 256;
                const float c0 = p[0],      c1 = p[65536],  c2 = p[131072], c3 = p[196608];
                const float c4 = p[262144], c5 = p[327680], c6 = p[393216], c7 = p[458752];
                q0 = pk2(c0, c1); q1 = pk2(c2, c3); q2 = pk2(c4, c5); q3 = pk2(c6, c7);
            }
            *(u32x4*)(ldst + r * ROWBYTES) = u32x4{q0, q1, q2, q3};
        }
    }
    __syncthreads();   // the only full barrier before compute

    // ---- compute: each wave does 4 output rows, barrier-free
    #pragma unroll
    for (int i = 0; i < 4; ++i) {
        const int hr = (wave << 2) + i;                   // 0..15

        f16v acc0, acc1;
        #pragma unroll
        for (int rg = 0; rg < 16; ++rg) { acc0[rg] = 0.f; acc1[rg] = 0.f; }

        #pragma unroll
        for (int kh = 0; kh < 3; ++kh) {
            const char* rowp = lds + (hr + kh) * ROWBYTES + g * 1056 + (ln << 4);
            #pragma unroll
            for (int kw = 0; kw < 3; ++kw) {
                const int tap = kh * 3 + kw;
                #pragma unroll
                for (int q = 0; q < 2; ++q) {
                    const char* pB = rowp + q * 2112 + (kw << 4);
                    const s8v b0 = *(const s8v*)pB;           // px = w0+ln+kw-1
                    const s8v b1 = *(const s8v*)(pB + 512);   // px +32
                    acc0 = __builtin_amdgcn_mfma_f32_32x32x16_bf16(A[tap][q], b0, acc0, 0, 0, 0);
                    acc1 = __builtin_amdgcn_mfma_f32_32x32x16_bf16(A[tap][q], b1, acc1, 0, 0, 0);
                }
            }
        }

        // epilogue: D col(px)=ln, row(o)=(rg&3)+8*(rg>>2)+4*g ; plain stores (L2 combine)
        const int h = h0 + hr;
        float* op = out + ((size_t)n << 21) + (size_t)h * 256 + w0 + ln;
        #pragma unroll
        for (int rg = 0; rg < 16; ++rg) {
            const int o = (rg & 3) + 8 * (rg >> 2) + 4 * g;
            op[(size_t)o * 65536]      = scale * acc0[rg] + bias_r[rg];
            op[(size_t)o * 65536 + 32] = scale * acc1[rg] + bias_r[rg];
        }
    }
}

extern "C" void kernel_launch(void* const* d_in, const int* in_sizes, int n_in,
                              void* d_out, int out_size, void* d_ws, size_t ws_size,
                              hipStream_t stream) {
    const float* x     = (const float*)d_in[0];
    const float* wgt   = (const float*)d_in[1];
    const float* bias  = (const float*)d_in[2];
    const float* scale = (const float*)d_in[3];
    float* out = (float*)d_out;
    k_fused<<<dim3(1024), dim3(256), 0, stream>>>(x, wgt, bias, scale, out);
}